// Round 8
// baseline (288.990 us; speedup 1.0000x reference)
//
#include <hip/hip_runtime.h>
#include <stdint.h>

#define TT 4096    // B*S tokens
#define DD 1024    // model dim
#define EE 8       // experts
#define HH 1792    // hidden dim
#define MP 10240   // max padded gathered rows (40*256)
#define MT256 40   // max 256-row tiles
#define MT128 80   // max 128-row tiles

typedef __attribute__((ext_vector_type(8))) short short8;    // 8 x bf16
typedef __attribute__((ext_vector_type(4))) short short4v;   // 4 x bf16
typedef __attribute__((ext_vector_type(4))) float f32x4;

static __device__ __forceinline__ unsigned short f2bf(float f) {
  union { float f; uint32_t u; } v; v.f = f;
  return (unsigned short)((v.u + 0x7fffu + ((v.u >> 16) & 1u)) >> 16);  // RNE
}
static __device__ __forceinline__ float bf2f(unsigned short h) {
  union { uint32_t u; float f; } v; v.u = ((uint32_t)h) << 16;
  return v.f;
}

// async global->LDS, 16B/lane; dest pattern base+tid*16 (verified in r7 kernel)
static __device__ __forceinline__ void gll16(const void* g, const void* l) {
  __builtin_amdgcn_global_load_lds(
      (const __attribute__((address_space(1))) unsigned int*)g,
      (__attribute__((address_space(3))) unsigned int*)l, 16, 0, 0);
}

// ---------------- weight transpose+convert: f32 [R][C] -> bf16 [C][R] ----------------
// ilv=1: dst row for source col c is (c>>4)*32 + sel*16 + (c&15)  (G/U 16-col interleave)
__global__ __launch_bounds__(256) void transpose_convert(
    const float* __restrict__ in, unsigned short* __restrict__ outp, int R, int C,
    int ilv, int sel) {
  __shared__ float t[64][68];
  const float* src = in + (size_t)blockIdx.z * R * C + (size_t)(blockIdx.x * 64) * C +
                     blockIdx.y * 64;
  unsigned short* dst = outp + (size_t)blockIdx.z * R * C * (ilv ? 2 : 1);
  const int tid = threadIdx.x;
  const int lr = tid >> 2, lc = (tid & 3) * 16;
#pragma unroll
  for (int q = 0; q < 4; ++q) {
    const f32x4 v = *(const f32x4*)(src + (size_t)lr * C + lc + 4 * q);
    t[lr][lc + 4 * q + 0] = v[0]; t[lr][lc + 4 * q + 1] = v[1];
    t[lr][lc + 4 * q + 2] = v[2]; t[lr][lc + 4 * q + 3] = v[3];
  }
  __syncthreads();
  unsigned short b[16];
#pragma unroll
  for (int q = 0; q < 16; ++q) b[q] = f2bf(t[lc + q][lr]);
  const int cg = blockIdx.y * 64 + lr;                       // source col (dst logical row)
  const int prow = ilv ? ((cg >> 4) * 32 + sel * 16 + (cg & 15)) : cg;
  unsigned short* d = dst + (size_t)prow * R + blockIdx.x * 64 + lc;
  *(short8*)(d) = *(const short8*)&b[0];
  *(short8*)(d + 8) = *(const short8*)&b[8];
}

// ---------------- gate: logits (bf16-emulated), top-2, combine, probs, topk ----------------
__global__ __launch_bounds__(256) void gate_kernel(
    const float* __restrict__ x, const float* __restrict__ gw,
    float* __restrict__ combine, float* __restrict__ probs, int2* __restrict__ topk) {
  const int lane = threadIdx.x & 63;
  const int wave = threadIdx.x >> 6;
  const int t = blockIdx.x * 4 + wave;
  const float* xr = x + (size_t)t * DD;
  float acc[EE];
#pragma unroll
  for (int e = 0; e < EE; ++e) acc[e] = 0.f;
  for (int i = 0; i < DD / 64; ++i) {
    const int d = i * 64 + lane;
    const float xv = bf2f(f2bf(xr[d]));
#pragma unroll
    for (int e = 0; e < EE; ++e)
      acc[e] += xv * bf2f(f2bf(gw[e * DD + d]));
  }
#pragma unroll
  for (int e = 0; e < EE; ++e) {
#pragma unroll
    for (int off = 32; off > 0; off >>= 1)
      acc[e] += __shfl_xor(acc[e], off, 64);
  }
  if (lane == 0) {
    float lg[EE];
#pragma unroll
    for (int e = 0; e < EE; ++e) lg[e] = bf2f(f2bf(acc[e]));
    float m1 = -1e30f, m2 = -1e30f; int i1 = 0, i2 = 0;
#pragma unroll
    for (int e = 0; e < EE; ++e) {
      const float v = lg[e];
      if (v > m1) { m2 = m1; i2 = i1; m1 = v; i1 = e; }
      else if (v > m2) { m2 = v; i2 = e; }
    }
    const float e2 = expf(m2 - m1);
    const float w1 = 1.f / (1.f + e2);
    const float w2 = e2 * w1;
    float cb[EE];
#pragma unroll
    for (int e = 0; e < EE; ++e) cb[e] = 0.f;
    cb[i1] = w1; cb[i2] += w2;
    float p[EE]; float s = 0.f;
#pragma unroll
    for (int e = 0; e < EE; ++e) { p[e] = expf(lg[e] - m1); s += p[e]; }
    const float inv = 1.f / s;
#pragma unroll
    for (int e = 0; e < EE; ++e) {
      combine[(size_t)t * EE + e] = cb[e];
      probs[(size_t)t * EE + e] = p[e] * inv;
    }
    topk[t] = make_int2(i1, i2);
  }
}

// ---------------- deterministic probs reduction -> mean_probs + loss ----------------
__global__ __launch_bounds__(256) void reduce_kernel(
    const float* __restrict__ probs, float* __restrict__ tail) {
  const int tid = threadIdx.x;
  const int lane = tid & 63, wave = tid >> 6;
  float acc[EE];
#pragma unroll
  for (int e = 0; e < EE; ++e) acc[e] = 0.f;
  for (int t = tid; t < TT; t += 256) {
#pragma unroll
    for (int e = 0; e < EE; ++e) acc[e] += probs[(size_t)t * EE + e];
  }
#pragma unroll
  for (int e = 0; e < EE; ++e) {
#pragma unroll
    for (int off = 32; off > 0; off >>= 1)
      acc[e] += __shfl_xor(acc[e], off, 64);
  }
  __shared__ float sm[4][EE];
  if (lane == 0) {
#pragma unroll
    for (int e = 0; e < EE; ++e) sm[wave][e] = acc[e];
  }
  __syncthreads();
  if (tid == 0) {
    float loss = 0.f;
#pragma unroll
    for (int e = 0; e < EE; ++e) {
      const float m = (sm[0][e] + sm[1][e] + sm[2][e] + sm[3][e]) * (1.f / TT);
      tail[1 + e] = m;
      loss += m * m;
    }
    tail[0] = (float)EE * loss;
  }
}

// ---------------- routing: compacted token lists (pad to 256) + tile tables ----------------
__global__ __launch_bounds__(512) void route_kernel(
    const int2* __restrict__ topk, const float* __restrict__ combine,
    int* __restrict__ tok_list, float* __restrict__ wt_list,
    int* __restrict__ tab256, int* __restrict__ tab128) {
  const int lane = threadIdx.x & 63;
  const int e = threadIdx.x >> 6;  // one wave per expert
  __shared__ int cnts[EE], offs[EE];
  int cnt = 0;
  for (int i = 0; i < TT / 64; ++i) {
    const int2 k2 = topk[i * 64 + lane];
    cnt += __popcll(__ballot(k2.x == e || k2.y == e));
  }
  if (lane == 0) cnts[e] = cnt;
  __syncthreads();
  if (threadIdx.x == 0) {
    int off = 0, n256 = 0, n128 = 0;
    for (int f = 0; f < EE; ++f) {
      offs[f] = off;
      const int pc = (cnts[f] + 255) & ~255;
      for (int j = 0; j < (pc >> 8); ++j) {
        tab256[2 * n256] = f; tab256[2 * n256 + 1] = off + 256 * j; ++n256;
      }
      for (int j = 0; j < (pc >> 7); ++j) {
        tab128[2 * n128] = f; tab128[2 * n128 + 1] = off + 128 * j; ++n128;
      }
      off += pc;
    }
    for (; n256 < MT256; ++n256) { tab256[2 * n256] = -1; tab256[2 * n256 + 1] = 0; }
    for (; n128 < MT128; ++n128) { tab128[2 * n128] = -1; tab128[2 * n128 + 1] = 0; }
  }
  __syncthreads();
  int pos = offs[e];
  for (int i = 0; i < TT / 64; ++i) {
    const int t = i * 64 + lane;
    const int2 k2 = topk[t];
    const bool sel = (k2.x == e || k2.y == e);
    const unsigned long long m = __ballot(sel);
    if (sel) {
      const int p = pos + __popcll(m & ((1ull << lane) - 1ull));
      tok_list[p] = t;
      wt_list[p] = combine[(size_t)t * EE + e];
    }
    pos += __popcll(m);
  }
  const int pc = (cnt + 255) & ~255;  // pad slots: token 0, weight 0
  for (int s = cnt + lane; s < pc; s += 64) {
    tok_list[offs[e] + s] = 0;
    wt_list[offs[e] + s] = 0.f;
  }
}

// ---------------- gather x rows (f32 -> bf16) into contiguous padded buffer ----------------
__global__ __launch_bounds__(256) void gather_x(
    const float* __restrict__ x, const int* __restrict__ tok_list,
    const int* __restrict__ tab256, unsigned short* __restrict__ xg) {
  const int e = tab256[2 * blockIdx.x];
  if (e < 0) return;
  const int row0 = tab256[2 * blockIdx.x + 1] + blockIdx.y * 16;
  const int tid = threadIdx.x;
#pragma unroll
  for (int i = 0; i < 16; ++i) {
    const int row = row0 + i;
    const int tok = tok_list[row];
    const f32x4 v = *(const f32x4*)(x + (size_t)tok * DD + tid * 4);
    unsigned short b[4] = {f2bf(v[0]), f2bf(v[1]), f2bf(v[2]), f2bf(v[3])};
    *(short4v*)(xg + (size_t)row * DD + tid * 4) = *(const short4v*)b;
  }
}

// ================= gate+up GEMM: 256x256 tile, 8-phase m201 schedule =================
// A=xg [row][DD] bf16, B=wguT interleaved [e][2H][DD] bf16. 512 thr (8 waves, 2M x 4N),
// per-wave out 128x64. LDS 128KB: 2 bufs x {AL,AH,BL,BH} 16KB half-tiles, BK=64.
// Swizzle: phys 16B-chunk = logical ^ (row&7), both sides (stage source pre-swizzled).
// Phase = {ds_read subtile; stage 1 half-tile (2 gll); barrier; lgkm0; 16 MFMA; barrier}.
// Stage placement (slot's last read 1+ phases before issue -> race-free by end-barrier):
//   ph1:S(t+1,BH) ph2:S(t+1,AH) ph3:S(t+2,BL) ph4:S(t+2,AL)
//   ph5:S(t+2,BH) ph6:S(t+2,AH) ph7:S(t+3,BL) ph8:S(t+3,AL)
// vmcnt(4) at ph4 retires through S(t+1,AH) -> tile t+1 fully landed before ph5 reads.
// vmcnt(4) at ph8 retires through S(t+2,AH) -> tile t+2 landed before next-ph1 reads.
// Prologue issues {BL0,AL0,BH0,AH0,BL1,AL1}, vmcnt(4) -> tile0 landed, 2 halves in flight.
#define MID_SYNC                                     \
  __builtin_amdgcn_sched_barrier(0);                 \
  __builtin_amdgcn_s_barrier();                      \
  asm volatile("s_waitcnt lgkmcnt(0)" ::: "memory"); \
  __builtin_amdgcn_sched_barrier(0);
#define MID_SYNC_V4                                  \
  __builtin_amdgcn_sched_barrier(0);                 \
  asm volatile("s_waitcnt vmcnt(4)" ::: "memory");   \
  __builtin_amdgcn_s_barrier();                      \
  __builtin_amdgcn_sched_barrier(0);
#define END_SYNC                                     \
  __builtin_amdgcn_sched_barrier(0);                 \
  __builtin_amdgcn_s_barrier();

__global__ __launch_bounds__(512, 2) void gemm256(
    const unsigned short* __restrict__ Ab, const unsigned short* __restrict__ Bb,
    const int* __restrict__ tab, unsigned short* __restrict__ act) {
  constexpr int K = DD;      // 1024
  constexpr int NK = K / 64; // 16 K-tiles
  constexpr int NNT = 14;    // 3584/256
  extern __shared__ char lds[];

  const int nwg = gridDim.x;  // 560, %8==0
  const int wgid = (blockIdx.x & 7) * (nwg >> 3) + (blockIdx.x >> 3);
  const int mt = wgid / NNT, nt = wgid % NNT;
  const int e = tab[2 * mt];
  if (e < 0) return;
  const int row0 = tab[2 * mt + 1];
  const int n0 = nt * 256;

  const int tid = threadIdx.x, lane = tid & 63, wave = tid >> 6;
  const int wm = (wave >> 2) * 128, wn = (wave & 3) * 64;
  const int fr = lane & 15, hi = lane >> 4;

  const unsigned short* At = Ab + (size_t)row0 * K;
  const unsigned short* Bt = Bb + ((size_t)e * 2 * HH + n0) * K;

  asm volatile("s_waitcnt vmcnt(0)" ::: "memory");  // exact gll accounting below

  // stage half-tile h (0=AL rows0-127, 1=AH, 2=BL, 3=BH) of K-tile u into buf p
  auto stage = [&](int u, int p, int h) {
    const unsigned short* src = (h >= 2) ? Bt : At;
    const int rbase = (h & 1) * 128;
#pragma unroll
    for (int q = 0; q < 2; ++q) {
      const int rel = q * 8192 + tid * 16;       // [0,16384)
      const int row = rel >> 7;                  // local row 0..127
      const int ch = (rel >> 4) & 7;
      gll16(src + (size_t)(rbase + row) * K + u * 64 + ((ch ^ (row & 7)) << 3),
            lds + p * 65536 + h * 16384 + rel);
    }
  };
  auto rdA = [&](int p, int m, int kc) -> short8 {
    const int lr = m & 127;
    return *(const short8*)(lds + p * 65536 + ((m >> 7) << 14) + lr * 128 +
                            ((((kc << 2) + hi) ^ (lr & 7)) << 4));
  };
  auto rdB = [&](int p, int n, int kc) -> short8 {
    const int lr = n & 127;
    return *(const short8*)(lds + p * 65536 + 32768 + ((n >> 7) << 14) + lr * 128 +
                            ((((kc << 2) + hi) ^ (lr & 7)) << 4));
  };

  f32x4 acc[8][4];
#pragma unroll
  for (int i = 0; i < 8; ++i)
#pragma unroll
    for (int j = 0; j < 4; ++j) acc[i][j] = (f32x4){0.f, 0.f, 0.f, 0.f};
  short8 a03[4][2], a47[4][2], b01[2][2], b23[2][2];  // static-indexed only

  // prologue
  stage(0, 0, 2); stage(0, 0, 0); stage(0, 0, 3); stage(0, 0, 1);
  stage(1, 1, 2); stage(1, 1, 0);
  asm volatile("s_waitcnt vmcnt(4)" ::: "memory");
  __builtin_amdgcn_s_barrier();

  // one K-tile = 4 phases; p is compile-time-per-call (0 for even tile, 1 for odd)
  auto ktile = [&](int p, int un1, int pn1, int un2, int pn2) {
    // ph1: read A03+B01; stage BH(un1); MFMA Q(m03,n01)
#pragma unroll
    for (int i = 0; i < 4; ++i)
#pragma unroll
      for (int kc = 0; kc < 2; ++kc) a03[i][kc] = rdA(p, wm + i * 16 + fr, kc);
#pragma unroll
    for (int j = 0; j < 2; ++j)
#pragma unroll
      for (int kc = 0; kc < 2; ++kc) b01[j][kc] = rdB(p, wn + j * 16 + fr, kc);
    stage(un1, pn1, 3);
    MID_SYNC
    __builtin_amdgcn_s_setprio(1);
#pragma unroll
    for (int i = 0; i < 4; ++i)
#pragma unroll
      for (int j = 0; j < 2; ++j)
#pragma unroll
        for (int kc = 0; kc < 2; ++kc)
          acc[i][j] = __builtin_amdgcn_mfma_f32_16x16x32_bf16(a03[i][kc], b01[j][kc], acc[i][j], 0, 0, 0);
    __builtin_amdgcn_s_setprio(0);
    END_SYNC
    // ph2: read B23; stage AH(un1); MFMA Q(m03,n23)
#pragma unroll
    for (int j = 0; j < 2; ++j)
#pragma unroll
      for (int kc = 0; kc < 2; ++kc) b23[j][kc] = rdB(p, wn + 32 + j * 16 + fr, kc);
    stage(un1, pn1, 1);
    MID_SYNC
    __builtin_amdgcn_s_setprio(1);
#pragma unroll
    for (int i = 0; i < 4; ++i)
#pragma unroll
      for (int j = 0; j < 2; ++j)
#pragma unroll
        for (int kc = 0; kc < 2; ++kc)
          acc[i][2 + j] = __builtin_amdgcn_mfma_f32_16x16x32_bf16(a03[i][kc], b23[j][kc], acc[i][2 + j], 0, 0, 0);
    __builtin_amdgcn_s_setprio(0);
    END_SYNC
    // ph3: read A47; stage BL(un2); MFMA Q(m47,n01)
#pragma unroll
    for (int i = 0; i < 4; ++i)
#pragma unroll
      for (int kc = 0; kc < 2; ++kc) a47[i][kc] = rdA(p, wm + 64 + i * 16 + fr, kc);
    stage(un2, pn2, 2);
    MID_SYNC
    __builtin_amdgcn_s_setprio(1);
#pragma unroll
    for (int i = 0; i < 4; ++i)
#pragma unroll
      for (int j = 0; j < 2; ++j)
#pragma unroll
        for (int kc = 0; kc < 2; ++kc)
          acc[4 + i][j] = __builtin_amdgcn_mfma_f32_16x16x32_bf16(a47[i][kc], b01[j][kc], acc[4 + i][j], 0, 0, 0);
    __builtin_amdgcn_s_setprio(0);
    END_SYNC
    // ph4: stage AL(un2); vmcnt(4); MFMA Q(m47,n23)
    stage(un2, pn2, 0);
    MID_SYNC_V4
    __builtin_amdgcn_s_setprio(1);
#pragma unroll
    for (int i = 0; i < 4; ++i)
#pragma unroll
      for (int j = 0; j < 2; ++j)
#pragma unroll
        for (int kc = 0; kc < 2; ++kc)
          acc[4 + i][2 + j] = __builtin_amdgcn_mfma_f32_16x16x32_bf16(a47[i][kc], b23[j][kc], acc[4 + i][2 + j], 0, 0, 0);
    __builtin_amdgcn_s_setprio(0);
    END_SYNC
  };

#pragma unroll 1
  for (int tt = 0; tt < NK; tt += 2) {
    // tail dummies re-stage the current (L2-hot, just-read) tiles — slot-safe, counts uniform
    const int u2 = (tt + 2 < NK) ? tt + 2 : tt;
    const int u3 = (tt + 3 < NK) ? tt + 3 : tt + 1;
    ktile(0, tt + 1, 1, u2, 0);  // tile tt   (buf0): ph1-4
    ktile(1, u2, 0, u3, 1);      // tile tt+1 (buf1): ph5-8
  }
  asm volatile("s_waitcnt vmcnt(0)" ::: "memory");

  const int r4 = hi * 4;
#pragma unroll
  for (int i = 0; i < 8; ++i)
#pragma unroll
    for (int r = 0; r < 4; ++r) {
      const int row = row0 + wm + i * 16 + r4 + r;
#pragma unroll
      for (int jj = 0; jj < 2; ++jj) {
        const float g = acc[i][2 * jj][r], u = acc[i][2 * jj + 1][r];
        const int nb = n0 + wn + jj * 32;
        const int h = ((nb >> 5) << 4) + fr;   // de-interleave to real H col
        act[(size_t)row * HH + h] = f2bf((g / (1.f + expf(-g))) * u);
      }
    }
}

// ---------------- down GEMM: verified m97 128x128 structure (unchanged from r7) ----------------
__global__ __launch_bounds__(256, 3) void gemm128d(
    const unsigned short* __restrict__ Ab, const unsigned short* __restrict__ Bb,
    const int* __restrict__ tab, const int* __restrict__ tok_list,
    const float* __restrict__ wt_list, float* __restrict__ out) {
  constexpr int K   = HH;    // 1792
  constexpr int NNT = 8;     // 1024/128
  __shared__ unsigned short As[128 * 64];
  __shared__ unsigned short Bs[128 * 64];

  const int nwg = gridDim.x;
  const int wgid = (blockIdx.x & 7) * (nwg >> 3) + (blockIdx.x >> 3);
  const int mt = wgid / NNT, nt = wgid % NNT;
  const int e = tab[2 * mt];
  if (e < 0) return;
  const int row0 = tab[2 * mt + 1];
  const int n0 = nt * 128;

  const int tid = threadIdx.x, lane = tid & 63, wave = tid >> 6;
  const int wm = (wave >> 1) * 64, wn = (wave & 1) * 64;
  const int fr = lane & 15, hi = lane >> 4;

  const unsigned short* At = Ab + (size_t)row0 * K;
  const unsigned short* Bt = Bb + ((size_t)e * DD + n0) * K;

  const int srel = tid * 16;
  const int srow0 = srel >> 7;
  const int sch = (srel >> 4) & 7;

  f32x4 acc[4][4];
#pragma unroll
  for (int i = 0; i < 4; ++i)
#pragma unroll
    for (int j = 0; j < 4; ++j) acc[i][j] = (f32x4){0.f, 0.f, 0.f, 0.f};

  for (int k0 = 0; k0 < K; k0 += 64) {
#pragma unroll
    for (int q = 0; q < 4; ++q) {
      const int row = q * 32 + srow0;
      gll16(At + (size_t)row * K + k0 + ((sch ^ (row & 7)) << 3),
            (const char*)As + q * 4096 + srel);
    }
#pragma unroll
    for (int q = 0; q < 4; ++q) {
      const int row = q * 32 + srow0;
      gll16(Bt + (size_t)row * K + k0 + ((sch ^ (row & 7)) << 3),
            (const char*)Bs + q * 4096 + srel);
    }
    __syncthreads();
#pragma unroll
    for (int kc = 0; kc < 2; ++kc) {
      short8 a[4], b[4];
#pragma unroll
      for (int i = 0; i < 4; ++i) {
        const int row = wm + i * 16 + fr;
        a[i] = *(const short8*)((const char*)As + ((row * 128 + kc * 64 + hi * 16) ^ ((row & 7) << 4)));
      }
#pragma unroll
      for (int j = 0; j < 4; ++j) {
        const int row = wn + j * 16 + fr;
        b[j] = *(const short8*)((const char*)Bs + ((row * 128 + kc * 64 + hi * 16) ^ ((row & 7) << 4)));
      }
#pragma unroll
      for (int i = 0; i < 4; ++i)
#pragma unroll
        for (int j = 0; j < 4; ++j)
          acc[i][j] = __builtin_amdgcn_mfma_f32_16x16x32_bf16(a[i], b[j], acc[i][j], 0, 0, 0);
    }
    __syncthreads();
  }

  const int r4 = hi * 4;
#pragma unroll
  for (int i = 0; i < 4; ++i)
#pragma unroll
    for (int r = 0; r < 4; ++r) {
      const int rl = row0 + wm + i * 16 + r4 + r;
      const int tok = tok_list[rl];
      const float wt = wt_list[rl];
      if (wt != 0.f) {
#pragma unroll
        for (int j = 0; j < 4; ++j)
          unsafeAtomicAdd(&out[(size_t)tok * DD + n0 + wn + j * 16 + fr],
                          acc[i][j][r] * wt);
      }
    }
}

extern "C" void kernel_launch(void* const* d_in, const int* in_sizes, int n_in,
                              void* d_out, int out_size, void* d_ws, size_t ws_size,
                              hipStream_t stream) {
  const float* x      = (const float*)d_in[0];
  const float* gw     = (const float*)d_in[1];
  const float* w_gate = (const float*)d_in[2];
  const float* w_up   = (const float*)d_in[3];
  const float* w_down = (const float*)d_in[4];
  float* out = (float*)d_out;
  float* tail = out + (size_t)TT * DD;  // [loss, mean_probs x 8]

  char* w = (char*)d_ws;
  size_t o = 0;
  auto carve = [&](size_t bytes) { char* p = w + o; o += (bytes + 255) & ~255ull; return p; };
  unsigned short* wguT = (unsigned short*)carve((size_t)EE * 2 * HH * DD * 2);  // interleaved G/U
  unsigned short* wdT  = (unsigned short*)carve((size_t)EE * DD * HH * 2);
  unsigned short* xg   = (unsigned short*)carve((size_t)MP * DD * 2);
  unsigned short* act  = (unsigned short*)carve((size_t)MP * HH * 2);
  float* combine = (float*)carve((size_t)TT * EE * 4);
  float* probs   = (float*)carve((size_t)TT * EE * 4);
  int2* topk     = (int2*)carve((size_t)TT * 8);
  int* tok_list  = (int*)carve((size_t)MP * 4);
  float* wt_list = (float*)carve((size_t)MP * 4);
  int* tab256    = (int*)carve((size_t)MT256 * 8);
  int* tab128    = (int*)carve((size_t)MT128 * 8);

  hipMemsetAsync(out, 0, (size_t)TT * DD * sizeof(float), stream);

  transpose_convert<<<dim3(DD / 64, HH / 64, EE), 256, 0, stream>>>(w_gate, wguT, DD, HH, 1, 0);
  transpose_convert<<<dim3(DD / 64, HH / 64, EE), 256, 0, stream>>>(w_up,   wguT, DD, HH, 1, 1);
  transpose_convert<<<dim3(HH / 64, DD / 64, EE), 256, 0, stream>>>(w_down, wdT,  HH, DD, 0, 0);

  gate_kernel<<<TT / 4, 256, 0, stream>>>(x, gw, combine, probs, topk);
  reduce_kernel<<<1, 256, 0, stream>>>(probs, tail);
  route_kernel<<<1, 512, 0, stream>>>(topk, combine, tok_list, wt_list, tab256, tab128);
  gather_x<<<dim3(MT256, 16), 256, 0, stream>>>(x, tok_list, tab256, xg);

  hipFuncSetAttribute(reinterpret_cast<const void*>(&gemm256),
                      hipFuncAttributeMaxDynamicSharedMemorySize, 131072);
  gemm256<<<MT256 * 14, 512, 131072, stream>>>(xg, wguT, tab256, act);
  gemm128d<<<MT128 * 8, 256, 0, stream>>>(act, wdT, tab128, tok_list, wt_list, out);
}

// Round 9
// 263.347 us; speedup vs baseline: 1.0974x; 1.0974x over previous
//
#include <hip/hip_runtime.h>
#include <stdint.h>

#define TT 4096    // B*S tokens
#define DD 1024    // model dim
#define EE 8       // experts
#define HH 1792    // hidden dim
#define MP 10240   // max padded gathered rows (40*256)
#define MT256 40   // max 256-row tiles
#define MT128 80   // max 128-row tiles

typedef __attribute__((ext_vector_type(8))) short short8;    // 8 x bf16
typedef __attribute__((ext_vector_type(4))) short short4v;   // 4 x bf16
typedef __attribute__((ext_vector_type(4))) float f32x4;

static __device__ __forceinline__ unsigned short f2bf(float f) {
  union { float f; uint32_t u; } v; v.f = f;
  return (unsigned short)((v.u + 0x7fffu + ((v.u >> 16) & 1u)) >> 16);  // RNE
}
static __device__ __forceinline__ float bf2f(unsigned short h) {
  union { uint32_t u; float f; } v; v.u = ((uint32_t)h) << 16;
  return v.f;
}

// async global->LDS, 16B/lane; dest pattern base+tid*16 (verified r7)
static __device__ __forceinline__ void gll16(const void* g, const void* l) {
  __builtin_amdgcn_global_load_lds(
      (const __attribute__((address_space(1))) unsigned int*)g,
      (__attribute__((address_space(3))) unsigned int*)l, 16, 0, 0);
}

// ---------------- unified weight prep: transpose+convert, ONE launch ----------------
// blocks [0,3584): (e, d-tile bx, h-tile by) -> w_gate AND w_up 64x64 tiles -> wguT
//   interleaved rows: gate h -> (h>>4)*32 + (h&15); up h -> +16. dst ld = DD.
// blocks [3584,7168): (e, h-tile bx, d-tile by) -> w_down tile -> wdT [D][H]. ld = HH.
// LDS pad 65 floats: column read-back is 2-way bank aliasing (free, m136).
__global__ __launch_bounds__(256) void prep_weights(
    const float* __restrict__ w_gate, const float* __restrict__ w_up,
    const float* __restrict__ w_down, unsigned short* __restrict__ wguT,
    unsigned short* __restrict__ wdT) {
  __shared__ float L0[64][65];
  __shared__ float L1[64][65];
  const int tid = threadIdx.x;
  const int lr = tid >> 2, lc = (tid & 3) * 16;
  int bid = blockIdx.x;
  if (bid < 3584) {
    const int e = bid / 448, r = bid % 448;
    const int bx = r / 28, by = r % 28;  // bx: d-tile(16), by: h-tile(28)
    const size_t so = (size_t)e * DD * HH + (size_t)(bx * 64) * HH + by * 64;
    const float* g = w_gate + so;
    const float* u = w_up + so;
#pragma unroll
    for (int q = 0; q < 4; ++q) {
      const f32x4 vg = *(const f32x4*)(g + (size_t)lr * HH + lc + 4 * q);
      const f32x4 vu = *(const f32x4*)(u + (size_t)lr * HH + lc + 4 * q);
#pragma unroll
      for (int j = 0; j < 4; ++j) {
        L0[lr][lc + 4 * q + j] = vg[j];
        L1[lr][lc + 4 * q + j] = vu[j];
      }
    }
    __syncthreads();
    unsigned short b0[16], b1[16];
#pragma unroll
    for (int q = 0; q < 16; ++q) {
      b0[q] = f2bf(L0[lc + q][lr]);
      b1[q] = f2bf(L1[lc + q][lr]);
    }
    const int h = by * 64 + lr;                    // source col (output logical row)
    const int pg = (h >> 4) * 32 + (h & 15);       // gate interleave row
    unsigned short* dst = wguT + (size_t)e * 2 * HH * DD + (size_t)bx * 64 + lc;
    *(short8*)(dst + (size_t)pg * DD) = *(const short8*)&b0[0];
    *(short8*)(dst + (size_t)pg * DD + 8) = *(const short8*)&b0[8];
    *(short8*)(dst + (size_t)(pg + 16) * DD) = *(const short8*)&b1[0];
    *(short8*)(dst + (size_t)(pg + 16) * DD + 8) = *(const short8*)&b1[8];
  } else {
    bid -= 3584;
    const int e = bid / 448, r = bid % 448;
    const int bx = r / 16, by = r % 16;  // bx: h-tile(28), by: d-tile(16)
    const float* src = w_down + (size_t)e * HH * DD + (size_t)(bx * 64) * DD + by * 64;
#pragma unroll
    for (int q = 0; q < 4; ++q) {
      const f32x4 v = *(const f32x4*)(src + (size_t)lr * DD + lc + 4 * q);
#pragma unroll
      for (int j = 0; j < 4; ++j) L0[lr][lc + 4 * q + j] = v[j];
    }
    __syncthreads();
    unsigned short b0[16];
#pragma unroll
    for (int q = 0; q < 16; ++q) b0[q] = f2bf(L0[lc + q][lr]);
    const int d = by * 64 + lr;
    unsigned short* dst = wdT + (size_t)e * DD * HH + (size_t)d * HH + bx * 64 + lc;
    *(short8*)(dst) = *(const short8*)&b0[0];
    *(short8*)(dst + 8) = *(const short8*)&b0[8];
  }
}

// ---------------- gate: logits (bf16-emulated), top-2, combine, probs, topk ----------------
__global__ __launch_bounds__(256) void gate_kernel(
    const float* __restrict__ x, const float* __restrict__ gw,
    float* __restrict__ combine, float* __restrict__ probs, int2* __restrict__ topk) {
  const int lane = threadIdx.x & 63;
  const int wave = threadIdx.x >> 6;
  const int t = blockIdx.x * 4 + wave;
  const float* xr = x + (size_t)t * DD;
  float acc[EE];
#pragma unroll
  for (int e = 0; e < EE; ++e) acc[e] = 0.f;
  for (int i = 0; i < DD / 64; ++i) {
    const int d = i * 64 + lane;
    const float xv = bf2f(f2bf(xr[d]));
#pragma unroll
    for (int e = 0; e < EE; ++e)
      acc[e] += xv * bf2f(f2bf(gw[e * DD + d]));
  }
#pragma unroll
  for (int e = 0; e < EE; ++e) {
#pragma unroll
    for (int off = 32; off > 0; off >>= 1)
      acc[e] += __shfl_xor(acc[e], off, 64);
  }
  if (lane == 0) {
    float lg[EE];
#pragma unroll
    for (int e = 0; e < EE; ++e) lg[e] = bf2f(f2bf(acc[e]));
    float m1 = -1e30f, m2 = -1e30f; int i1 = 0, i2 = 0;
#pragma unroll
    for (int e = 0; e < EE; ++e) {
      const float v = lg[e];
      if (v > m1) { m2 = m1; i2 = i1; m1 = v; i1 = e; }
      else if (v > m2) { m2 = v; i2 = e; }
    }
    const float e2 = expf(m2 - m1);
    const float w1 = 1.f / (1.f + e2);
    const float w2 = e2 * w1;
    float cb[EE];
#pragma unroll
    for (int e = 0; e < EE; ++e) cb[e] = 0.f;
    cb[i1] = w1; cb[i2] += w2;
    float p[EE]; float s = 0.f;
#pragma unroll
    for (int e = 0; e < EE; ++e) { p[e] = expf(lg[e] - m1); s += p[e]; }
    const float inv = 1.f / s;
#pragma unroll
    for (int e = 0; e < EE; ++e) {
      combine[(size_t)t * EE + e] = cb[e];
      probs[(size_t)t * EE + e] = p[e] * inv;
    }
    topk[t] = make_int2(i1, i2);
  }
}

// ---------------- deterministic probs reduction -> mean_probs + loss ----------------
__global__ __launch_bounds__(256) void reduce_kernel(
    const float* __restrict__ probs, float* __restrict__ tail) {
  const int tid = threadIdx.x;
  const int lane = tid & 63, wave = tid >> 6;
  float acc[EE];
#pragma unroll
  for (int e = 0; e < EE; ++e) acc[e] = 0.f;
  for (int t = tid; t < TT; t += 256) {
#pragma unroll
    for (int e = 0; e < EE; ++e) acc[e] += probs[(size_t)t * EE + e];
  }
#pragma unroll
  for (int e = 0; e < EE; ++e) {
#pragma unroll
    for (int off = 32; off > 0; off >>= 1)
      acc[e] += __shfl_xor(acc[e], off, 64);
  }
  __shared__ float sm[4][EE];
  if (lane == 0) {
#pragma unroll
    for (int e = 0; e < EE; ++e) sm[wave][e] = acc[e];
  }
  __syncthreads();
  if (tid == 0) {
    float loss = 0.f;
#pragma unroll
    for (int e = 0; e < EE; ++e) {
      const float m = (sm[0][e] + sm[1][e] + sm[2][e] + sm[3][e]) * (1.f / TT);
      tail[1 + e] = m;
      loss += m * m;
    }
    tail[0] = (float)EE * loss;
  }
}

// ---------------- routing: compacted token lists (pad to 256) + tile tables ----------------
__global__ __launch_bounds__(512) void route_kernel(
    const int2* __restrict__ topk, const float* __restrict__ combine,
    int* __restrict__ tok_list, float* __restrict__ wt_list,
    int* __restrict__ tab256, int* __restrict__ tab128) {
  const int lane = threadIdx.x & 63;
  const int e = threadIdx.x >> 6;  // one wave per expert
  __shared__ int cnts[EE], offs[EE];
  int cnt = 0;
  for (int i = 0; i < TT / 64; ++i) {
    const int2 k2 = topk[i * 64 + lane];
    cnt += __popcll(__ballot(k2.x == e || k2.y == e));
  }
  if (lane == 0) cnts[e] = cnt;
  __syncthreads();
  if (threadIdx.x == 0) {
    int off = 0, n256 = 0, n128 = 0;
    for (int f = 0; f < EE; ++f) {
      offs[f] = off;
      const int pc = (cnts[f] + 255) & ~255;
      for (int j = 0; j < (pc >> 8); ++j) {
        tab256[2 * n256] = f; tab256[2 * n256 + 1] = off + 256 * j; ++n256;
      }
      for (int j = 0; j < (pc >> 7); ++j) {
        tab128[2 * n128] = f; tab128[2 * n128 + 1] = off + 128 * j; ++n128;
      }
      off += pc;
    }
    for (; n256 < MT256; ++n256) { tab256[2 * n256] = -1; tab256[2 * n256 + 1] = 0; }
    for (; n128 < MT128; ++n128) { tab128[2 * n128] = -1; tab128[2 * n128 + 1] = 0; }
  }
  __syncthreads();
  int pos = offs[e];
  for (int i = 0; i < TT / 64; ++i) {
    const int t = i * 64 + lane;
    const int2 k2 = topk[t];
    const bool sel = (k2.x == e || k2.y == e);
    const unsigned long long m = __ballot(sel);
    if (sel) {
      const int p = pos + __popcll(m & ((1ull << lane) - 1ull));
      tok_list[p] = t;
      wt_list[p] = combine[(size_t)t * EE + e];
    }
    pos += __popcll(m);
  }
  const int pc = (cnt + 255) & ~255;  // pad slots: token 0, weight 0
  for (int s = cnt + lane; s < pc; s += 64) {
    tok_list[offs[e] + s] = 0;
    wt_list[offs[e] + s] = 0.f;
  }
}

// ---------------- gather x rows (f32 -> bf16) into contiguous padded buffer ----------------
__global__ __launch_bounds__(256) void gather_x(
    const float* __restrict__ x, const int* __restrict__ tok_list,
    const int* __restrict__ tab256, unsigned short* __restrict__ xg) {
  const int e = tab256[2 * blockIdx.x];
  if (e < 0) return;
  const int row0 = tab256[2 * blockIdx.x + 1] + blockIdx.y * 16;
  const int tid = threadIdx.x;
#pragma unroll
  for (int i = 0; i < 16; ++i) {
    const int row = row0 + i;
    const int tok = tok_list[row];
    const f32x4 v = *(const f32x4*)(x + (size_t)tok * DD + tid * 4);
    unsigned short b[4] = {f2bf(v[0]), f2bf(v[1]), f2bf(v[2]), f2bf(v[3])};
    *(short4v*)(xg + (size_t)row * DD + tid * 4) = *(const short4v*)b;
  }
}

// ---------------- grouped GEMM: m97 structure (verified r7: 86.5us, 0 conflicts) ----------------
// 128x128 tile, 4 waves, BK=64, single 32KB LDS buffer, gll staging, TLP hides barrier drain.
// MODE 0: A=xg [row][DD], B=wguT interleaved [e][2H][DD]; epilogue silu(g)*u -> act bf16
// MODE 1: A=act [row][HH], B=wdT [e][DD][HH]; epilogue atomic scatter * combine wt
// LDS rows 128B; swizzle: phys 16B-chunk = logical ^ (row&7), both sides.
template <int MODE>
__global__ __launch_bounds__(256, 3) void gemm128(
    const unsigned short* __restrict__ Ab, const unsigned short* __restrict__ Bb,
    const int* __restrict__ tab, const int* __restrict__ tok_list,
    const float* __restrict__ wt_list, unsigned short* __restrict__ act,
    float* __restrict__ out) {
  constexpr int K   = (MODE == 0) ? DD : HH;     // 1024 / 1792
  constexpr int NBR = (MODE == 0) ? 2 * HH : DD; // B rows per expert
  constexpr int NNT = NBR / 128;                 // 28 / 8
  __shared__ unsigned short As[128 * 64];
  __shared__ unsigned short Bs[128 * 64];

  const int nwg = gridDim.x;  // %8==0 for both modes
  const int wgid = (blockIdx.x & 7) * (nwg >> 3) + (blockIdx.x >> 3);
  const int mt = wgid / NNT, nt = wgid % NNT;
  const int e = tab[2 * mt];
  if (e < 0) return;
  const int row0 = tab[2 * mt + 1];
  const int n0 = nt * 128;

  const int tid = threadIdx.x, lane = tid & 63, wave = tid >> 6;
  const int wm = (wave >> 1) * 64, wn = (wave & 1) * 64;
  const int fr = lane & 15, hi = lane >> 4;

  const unsigned short* At = Ab + (size_t)row0 * K;
  const unsigned short* Bt = Bb + ((size_t)e * NBR + n0) * K;

  // staging: pass q covers LDS bytes [q*4096, q*4096+4096), rows q*32+srow0
  const int srel = tid * 16;
  const int srow0 = srel >> 7;
  const int sch = (srel >> 4) & 7;

  f32x4 acc[4][4];
#pragma unroll
  for (int i = 0; i < 4; ++i)
#pragma unroll
    for (int j = 0; j < 4; ++j) acc[i][j] = (f32x4){0.f, 0.f, 0.f, 0.f};

  for (int k0 = 0; k0 < K; k0 += 64) {
#pragma unroll
    for (int q = 0; q < 4; ++q) {  // A tile: 16KB
      const int row = q * 32 + srow0;
      gll16(At + (size_t)row * K + k0 + ((sch ^ (row & 7)) << 3),
            (const char*)As + q * 4096 + srel);
    }
#pragma unroll
    for (int q = 0; q < 4; ++q) {  // B tile: 16KB
      const int row = q * 32 + srow0;
      gll16(Bt + (size_t)row * K + k0 + ((sch ^ (row & 7)) << 3),
            (const char*)Bs + q * 4096 + srel);
    }
    __syncthreads();  // compiler drains vmcnt+lgkmcnt
#pragma unroll
    for (int kc = 0; kc < 2; ++kc) {
      short8 a[4], b[4];
#pragma unroll
      for (int i = 0; i < 4; ++i) {
        const int row = wm + i * 16 + fr;
        a[i] = *(const short8*)((const char*)As + ((row * 128 + kc * 64 + hi * 16) ^ ((row & 7) << 4)));
      }
#pragma unroll
      for (int j = 0; j < 4; ++j) {
        const int row = wn + j * 16 + fr;
        b[j] = *(const short8*)((const char*)Bs + ((row * 128 + kc * 64 + hi * 16) ^ ((row & 7) << 4)));
      }
#pragma unroll
      for (int i = 0; i < 4; ++i)
#pragma unroll
        for (int j = 0; j < 4; ++j)
          acc[i][j] = __builtin_amdgcn_mfma_f32_16x16x32_bf16(a[i], b[j], acc[i][j], 0, 0, 0);
    }
    __syncthreads();
  }

  const int r4 = hi * 4;
  if constexpr (MODE == 0) {
#pragma unroll
    for (int i = 0; i < 4; ++i)
#pragma unroll
      for (int r = 0; r < 4; ++r) {
        const int row = row0 + wm + i * 16 + r4 + r;
#pragma unroll
        for (int jj = 0; jj < 2; ++jj) {
          const float g = acc[i][2 * jj][r], u = acc[i][2 * jj + 1][r];
          const int nb = n0 + wn + jj * 32;
          const int h = ((nb >> 5) << 4) + fr;   // de-interleave to real H col
          act[(size_t)row * HH + h] = f2bf((g / (1.f + expf(-g))) * u);
        }
      }
  } else {
#pragma unroll
    for (int i = 0; i < 4; ++i)
#pragma unroll
      for (int r = 0; r < 4; ++r) {
        const int rl = row0 + wm + i * 16 + r4 + r;
        const int tok = tok_list[rl];
        const float wt = wt_list[rl];
        if (wt != 0.f) {
#pragma unroll
          for (int j = 0; j < 4; ++j)
            unsafeAtomicAdd(&out[(size_t)tok * DD + n0 + wn + j * 16 + fr],
                            acc[i][j][r] * wt);
        }
      }
  }
}

extern "C" void kernel_launch(void* const* d_in, const int* in_sizes, int n_in,
                              void* d_out, int out_size, void* d_ws, size_t ws_size,
                              hipStream_t stream) {
  const float* x      = (const float*)d_in[0];
  const float* gw     = (const float*)d_in[1];
  const float* w_gate = (const float*)d_in[2];
  const float* w_up   = (const float*)d_in[3];
  const float* w_down = (const float*)d_in[4];
  float* out = (float*)d_out;
  float* tail = out + (size_t)TT * DD;  // [loss, mean_probs x 8]

  char* w = (char*)d_ws;
  size_t o = 0;
  auto carve = [&](size_t bytes) { char* p = w + o; o += (bytes + 255) & ~255ull; return p; };
  unsigned short* wguT = (unsigned short*)carve((size_t)EE * 2 * HH * DD * 2);  // interleaved G/U
  unsigned short* wdT  = (unsigned short*)carve((size_t)EE * DD * HH * 2);
  unsigned short* xg   = (unsigned short*)carve((size_t)MP * DD * 2);
  unsigned short* act  = (unsigned short*)carve((size_t)MP * HH * 2);
  float* combine = (float*)carve((size_t)TT * EE * 4);
  float* probs   = (float*)carve((size_t)TT * EE * 4);
  int2* topk     = (int2*)carve((size_t)TT * 8);
  int* tok_list  = (int*)carve((size_t)MP * 4);
  float* wt_list = (float*)carve((size_t)MP * 4);
  int* tab256    = (int*)carve((size_t)MT256 * 8);
  int* tab128    = (int*)carve((size_t)MT128 * 8);

  hipMemsetAsync(out, 0, (size_t)TT * DD * sizeof(float), stream);

  prep_weights<<<7168, 256, 0, stream>>>(w_gate, w_up, w_down, wguT, wdT);

  gate_kernel<<<TT / 4, 256, 0, stream>>>(x, gw, combine, probs, topk);
  reduce_kernel<<<1, 256, 0, stream>>>(probs, tail);
  route_kernel<<<1, 512, 0, stream>>>(topk, combine, tok_list, wt_list, tab256, tab128);
  gather_x<<<dim3(MT256, 16), 256, 0, stream>>>(x, tok_list, tab256, xg);

  gemm128<0><<<MT128 * 28, 256, 0, stream>>>(xg, wguT, tab128, nullptr, nullptr, act, nullptr);
  gemm128<1><<<MT128 * 8, 256, 0, stream>>>(act, wdT, tab128, tok_list, wt_list, nullptr, out);
}